// Round 13
// baseline (323.233 us; speedup 1.0000x reference)
//
#include <hip/hip_runtime.h>

#define NN 100000
#define NE 1250000
#define CIN 64
#define CH 64
#define CO 32
#define NG 128
#define NBLK ((NN + 255) / 256)    // 391 (node-grid for scans)
#define NBUCK 98                    // buckets of 1024 nodes: dst>>10 in [0,97]
#define BSHIFT 10
#define EPB 2048                    // edges per partition block
#define NBLKP ((NE + EPB - 1) / EPB) // 611
#define GGRID 2048                  // persistent-ish GEMM grid

// ---------------- init: zero sums+bhist, per-graph counts (block 0) -----------
static __global__ void k_zero(float* __restrict__ sums, int* __restrict__ bhist,
                              const int* __restrict__ batch, float* __restrict__ counts) {
  int i = blockIdx.x * 256 + threadIdx.x;
  if (i < NG * CO) sums[i] = 0.0f;
  if (i < 128) bhist[i] = 0;
  if (blockIdx.x == 0 && threadIdx.x < NG) {
    int g = threadIdx.x;
    int lo = 0, hi = NN;
    while (lo < hi) { int m = (lo + hi) >> 1; if (batch[m] < g) lo = m + 1; else hi = m; }
    int lb = lo;
    lo = 0; hi = NN;
    while (lo < hi) { int m = (lo + hi) >> 1; if (batch[m] <= g) lo = m + 1; else hi = m; }
    counts[g] = (float)(lo - lb);
  }
}

// ---------------- bucket histogram (LDS-staged) ----------------
static __global__ __launch_bounds__(256) void k_bhist(const int* __restrict__ dst,
                                                      int* __restrict__ bhist) {
  __shared__ int lh[128];
  if (threadIdx.x < 128) lh[threadIdx.x] = 0;
  __syncthreads();
  int e0 = blockIdx.x * EPB, e1 = min(e0 + EPB, NE);
  for (int e = e0 + threadIdx.x; e < e1; e += 256)
    atomicAdd(&lh[dst[e] >> BSHIFT], 1);
  __syncthreads();
  if (threadIdx.x < 128) { int v = lh[threadIdx.x]; if (v) atomicAdd(&bhist[threadIdx.x], v); }
}

// ---------------- exclusive scan of bucket counts (1 block, 128 thr) ----------
static __global__ void k_bscan(const int* __restrict__ bhist, int* __restrict__ bbase,
                               int* __restrict__ bcursor) {
  __shared__ int tmp[128];
  int t = threadIdx.x;
  int v = bhist[t];
  tmp[t] = v;
  __syncthreads();
  for (int off = 1; off < 128; off <<= 1) {
    int a = (t >= off) ? tmp[t - off] : 0;
    __syncthreads();
    tmp[t] += a;
    __syncthreads();
  }
  int ex = tmp[t] - v;
  bbase[t] = ex;
  bcursor[t] = ex;
  if (t == 127) bbase[128] = tmp[127];  // == NE
}

// ------- partition edges into bucket-grouped (src,dst) pair runs --------------
static __global__ __launch_bounds__(256) void k_part(const int* __restrict__ src,
                                                     const int* __restrict__ dst,
                                                     int* __restrict__ bcursor,
                                                     int2* __restrict__ pairs) {
  __shared__ int lh[128], lbase[128], loff[128];
  if (threadIdx.x < 128) { lh[threadIdx.x] = 0; loff[threadIdx.x] = 0; }
  __syncthreads();
  int e0 = blockIdx.x * EPB, e1 = min(e0 + EPB, NE);
  for (int e = e0 + threadIdx.x; e < e1; e += 256)
    atomicAdd(&lh[dst[e] >> BSHIFT], 1);
  __syncthreads();
  if (threadIdx.x < 128) {
    int v = lh[threadIdx.x];
    lbase[threadIdx.x] = v ? atomicAdd(&bcursor[threadIdx.x], v) : 0;
  }
  __syncthreads();
  for (int e = e0 + threadIdx.x; e < e1; e += 256) {
    int d = dst[e], b = d >> BSHIFT;
    int o = atomicAdd(&loff[b], 1);
    pairs[lbase[b] + o] = make_int2(src[e], d);
  }
}

// ------- per-bucket degree via LDS histogram; coalesced degi/dinv writes ------
static __global__ __launch_bounds__(256) void k_bucket_a(const int2* __restrict__ pairs,
                                                         const int* __restrict__ bbase,
                                                         int* __restrict__ degi,
                                                         float* __restrict__ dinv) {
  __shared__ int lh[1024];
  for (int t = threadIdx.x; t < 1024; t += 256) lh[t] = 0;
  __syncthreads();
  int b = blockIdx.x;
  int p0 = bbase[b], p1 = bbase[b + 1];
  for (int p = p0 + threadIdx.x; p < p1; p += 256)
    atomicAdd(&lh[pairs[p].y & 1023], 1);
  __syncthreads();
  int nb = b << BSHIFT;
  for (int t = threadIdx.x; t < 1024; t += 256) {
    int node = nb + t;
    if (node < NN) { int dg = lh[t]; degi[node] = dg; dinv[node] = rsqrtf((float)dg + 1.0f); }
  }
}

// ---------------- prefix scan of degrees -> CSR row starts ----------------
static __global__ void k_scanA(const int* __restrict__ degi, int* __restrict__ bsum) {
  __shared__ int tmp[256];
  int i = blockIdx.x * 256 + threadIdx.x;
  int v = (i < NN) ? degi[i] : 0;
  tmp[threadIdx.x] = v;
  __syncthreads();
  for (int off = 128; off > 0; off >>= 1) {
    if (threadIdx.x < off) tmp[threadIdx.x] += tmp[threadIdx.x + off];
    __syncthreads();
  }
  if (threadIdx.x == 0) bsum[blockIdx.x] = tmp[0];
}

static __global__ void k_scanB(const int* __restrict__ bsum, int* __restrict__ bbase2) {
  __shared__ int tmp[512];
  int t = threadIdx.x;
  int v = (t < NBLK) ? bsum[t] : 0;
  tmp[t] = v;
  __syncthreads();
  for (int off = 1; off < 512; off <<= 1) {
    int add = (t >= off) ? tmp[t - off] : 0;
    __syncthreads();
    tmp[t] += add;
    __syncthreads();
  }
  if (t < NBLK) bbase2[t] = tmp[t] - v;  // exclusive
}

static __global__ void k_scanC(const int* __restrict__ degi, const int* __restrict__ bbase2,
                               int* __restrict__ rowstart) {
  __shared__ int tmp[256];
  int i = blockIdx.x * 256 + threadIdx.x;
  int v = (i < NN) ? degi[i] : 0;
  tmp[threadIdx.x] = v;
  __syncthreads();
  for (int off = 1; off < 256; off <<= 1) {
    int add = (threadIdx.x >= off) ? tmp[threadIdx.x - off] : 0;
    __syncthreads();
    tmp[threadIdx.x] += add;
    __syncthreads();
  }
  if (i < NN) rowstart[i] = bbase2[blockIdx.x] + tmp[threadIdx.x] - v;  // exclusive
}

// ------- per-bucket CSR scatter with LDS cursors (localized writes) -----------
static __global__ __launch_bounds__(256) void k_bucket_b(const int2* __restrict__ pairs,
                                                         const int* __restrict__ bbase,
                                                         const int* __restrict__ rowstart,
                                                         int* __restrict__ csr_src) {
  __shared__ int cur[1024];
  int b = blockIdx.x, nb = b << BSHIFT;
  for (int t = threadIdx.x; t < 1024; t += 256) {
    int node = nb + t;
    cur[t] = (node < NN) ? rowstart[node] : 0;
  }
  __syncthreads();
  int p0 = bbase[b], p1 = bbase[b + 1];
  for (int p = p0 + threadIdx.x; p < p1; p += 256) {
    int2 pr = pairs[p];
    int pos = atomicAdd(&cur[pr.y & 1023], 1);
    csr_src[pos] = pr.x;
  }
}

// -- GEMM 1: h' = dinv*(x @ W1); persistent blocks, W staged ONCE per block ----
static __global__ __launch_bounds__(256) void k_gemm1(const float* __restrict__ x,
                                                      const float* __restrict__ W,
                                                      const float* __restrict__ dinv,
                                                      float* __restrict__ h) {
  __shared__ float Ws[CIN * CH];
  for (int t = threadIdx.x; t < CIN * CH; t += 256) Ws[t] = W[t];
  __syncthreads();
  int wave = threadIdx.x >> 6;
  int lane = threadIdx.x & 63;
  for (int row = blockIdx.x * 4 + wave; row < NN; row += GGRID * 4) {
    const float4* xr = reinterpret_cast<const float4*>(x + row * CIN);
    float acc = 0.0f;
#pragma unroll
    for (int k4 = 0; k4 < CIN / 4; ++k4) {
      float4 xv = xr[k4];
      acc += xv.x * Ws[(k4 * 4 + 0) * CH + lane];
      acc += xv.y * Ws[(k4 * 4 + 1) * CH + lane];
      acc += xv.z * Ws[(k4 * 4 + 2) * CH + lane];
      acc += xv.w * Ws[(k4 * 4 + 3) * CH + lane];
    }
    h[row * CH + lane] = acc * dinv[row];
  }
}

// ------- layer-1 agg: agg[i] = dinv[i] * (h'[i] + sum_{s in N(i)} h'[s]) ------
static __global__ __launch_bounds__(256) void k_agg64(const float* __restrict__ h,
                                                      const float* __restrict__ dinv,
                                                      const int* __restrict__ rowstart,
                                                      const int* __restrict__ degi,
                                                      const int* __restrict__ csr_src,
                                                      float* __restrict__ agg) {
  int wave = threadIdx.x >> 6, lane = threadIdx.x & 63;
  int i = blockIdx.x * 4 + wave;  // grid exact: 25000*4
  float acc = h[i * CH + lane];   // self-loop (h already dinv-scaled)
  int s0 = rowstart[i], n = degi[i];
  int k = 0;
  for (; k + 3 < n; k += 4) {
    int sA = csr_src[s0 + k];
    int sB = csr_src[s0 + k + 1];
    int sC = csr_src[s0 + k + 2];
    int sD = csr_src[s0 + k + 3];
    float a = h[sA * CH + lane];
    float b = h[sB * CH + lane];
    float c = h[sC * CH + lane];
    float d = h[sD * CH + lane];
    acc += (a + b) + (c + d);
  }
  for (; k < n; ++k) acc += h[csr_src[s0 + k] * CH + lane];
  agg[i * CH + lane] = acc * dinv[i];
}

// -- GEMM 2: h2' = dinv*(relu(agg1+b1) @ W2); persistent blocks ---------------
static __global__ __launch_bounds__(256) void k_gemm2(const float* __restrict__ agg1,
                                                      const float* __restrict__ W,
                                                      const float* __restrict__ b1,
                                                      const float* __restrict__ dinv,
                                                      float* __restrict__ h2) {
  __shared__ float Ws[CH * CO];
  __shared__ float bs[CH];
  for (int t = threadIdx.x; t < CH * CO; t += 256) Ws[t] = W[t];
  if (threadIdx.x < CH) bs[threadIdx.x] = b1[threadIdx.x];
  __syncthreads();
  int half = threadIdx.x >> 5;
  int j = threadIdx.x & 31;
  for (int row = blockIdx.x * 8 + half; row < NN; row += GGRID * 8) {
    const float4* ar = reinterpret_cast<const float4*>(agg1 + row * CH);
    float acc = 0.0f;
#pragma unroll
    for (int k4 = 0; k4 < CH / 4; ++k4) {
      float4 av = ar[k4];
      float v0 = av.x + bs[k4 * 4 + 0]; v0 = v0 > 0.f ? v0 : 0.f;
      float v1 = av.y + bs[k4 * 4 + 1]; v1 = v1 > 0.f ? v1 : 0.f;
      float v2 = av.z + bs[k4 * 4 + 2]; v2 = v2 > 0.f ? v2 : 0.f;
      float v3 = av.w + bs[k4 * 4 + 3]; v3 = v3 > 0.f ? v3 : 0.f;
      acc += v0 * Ws[(k4 * 4 + 0) * CO + j];
      acc += v1 * Ws[(k4 * 4 + 1) * CO + j];
      acc += v2 * Ws[(k4 * 4 + 2) * CO + j];
      acc += v3 * Ws[(k4 * 4 + 3) * CO + j];
    }
    h2[row * CO + j] = acc * dinv[row];
  }
}

// ---- layer-2 agg + bias + mean-pool partial (LDS run-reduction) --------------
static __global__ __launch_bounds__(256) void k_agg32pool(const float* __restrict__ h2,
                                                          const float* __restrict__ dinv,
                                                          const int* __restrict__ rowstart,
                                                          const int* __restrict__ degi,
                                                          const int* __restrict__ csr_src,
                                                          const int* __restrict__ batch,
                                                          const float* __restrict__ b2,
                                                          float* __restrict__ sums) {
  __shared__ float vals[8][CO];
  __shared__ int gid[8];
  int half = threadIdx.x >> 5;  // 0..7 (node slot)
  int c = threadIdx.x & 31;
  int i = blockIdx.x * 8 + half;  // grid exact: 12500*8
  float acc = h2[i * CO + c];     // self-loop (h2 already dinv-scaled)
  int s0 = rowstart[i], n = degi[i];
  int k = 0;
  for (; k + 3 < n; k += 4) {
    int sA = csr_src[s0 + k];
    int sB = csr_src[s0 + k + 1];
    int sC = csr_src[s0 + k + 2];
    int sD = csr_src[s0 + k + 3];
    float a = h2[sA * CO + c];
    float b = h2[sB * CO + c];
    float cc = h2[sC * CO + c];
    float d = h2[sD * CO + c];
    acc += (a + b) + (cc + d);
  }
  for (; k < n; ++k) acc += h2[csr_src[s0 + k] * CO + c];
  vals[half][c] = acc * dinv[i] + b2[c];
  if (c == 0) gid[half] = batch[i];
  __syncthreads();
  if (threadIdx.x < 32) {
    int ch = threadIdx.x;
    float run = vals[0][ch];
    int g = gid[0];
    for (int s = 1; s < 8; ++s) {
      if (gid[s] == g) run += vals[s][ch];
      else { atomicAdd(&sums[g * CO + ch], run); g = gid[s]; run = vals[s][ch]; }
    }
    atomicAdd(&sums[g * CO + ch], run);
  }
}

static __global__ void k_final(const float* __restrict__ sums, const float* __restrict__ counts,
                               float* __restrict__ out) {
  int t = blockIdx.x * 256 + threadIdx.x;
  if (t >= NG * CO) return;
  out[t] = sums[t] / fmaxf(counts[t >> 5], 1.0f);
}

extern "C" void kernel_launch(void* const* d_in, const int* in_sizes, int n_in,
                              void* d_out, int out_size, void* d_ws, size_t ws_size,
                              hipStream_t stream) {
  const float* x   = (const float*)d_in[0];
  const int* ei    = (const int*)d_in[1];   // [2, NE]: src = ei, dst = ei+NE
  const int* batch = (const int*)d_in[2];
  const float* W1  = (const float*)d_in[3];
  const float* b1  = (const float*)d_in[4];
  const float* W2  = (const float*)d_in[5];
  const float* b2  = (const float*)d_in[6];
  float* out = (float*)d_out;

  const int* src = ei;
  const int* dst = ei + NE;

  char* base = (char*)d_ws;
  size_t off = 0;
  auto alloc = [&](size_t nelem) {
    void* p = (void*)(base + off);
    off += ((nelem * 4 + 255) / 256) * 256;
    return p;
  };
  int* degi      = (int*)alloc(NN);
  int* rowstart  = (int*)alloc(NN);
  float* dinv    = (float*)alloc(NN);
  int* bsum      = (int*)alloc(NBLK);
  int* bbase2    = (int*)alloc(NBLK);
  int* bhist     = (int*)alloc(128);
  int* bbase     = (int*)alloc(129);
  int* bcursor   = (int*)alloc(128);
  int* csr_src   = (int*)alloc(NE);                 // 5 MB
  float* bufA    = (float*)alloc((size_t)NN * CH);  // h1' then h2'
  float* bufB    = (float*)alloc((size_t)NN * CH);  // pairs (10 MB) then agg1
  float* sums    = (float*)alloc(NG * CO);
  float* counts  = (float*)alloc(NG);
  int2* pairs    = (int2*)bufB;  // dead once k_bucket_b finishes; agg64 then owns bufB

  dim3 B(256);
  // CSR build (bucketed, cache-friendly)
  k_zero<<<dim3(16), B, 0, stream>>>(sums, bhist, batch, counts);
  k_bhist<<<dim3(NBLKP), B, 0, stream>>>(dst, bhist);
  k_bscan<<<dim3(1), dim3(128), 0, stream>>>(bhist, bbase, bcursor);
  k_part<<<dim3(NBLKP), B, 0, stream>>>(src, dst, bcursor, pairs);
  k_bucket_a<<<dim3(NBUCK), B, 0, stream>>>(pairs, bbase, degi, dinv);
  k_scanA<<<dim3(NBLK), B, 0, stream>>>(degi, bsum);
  k_scanB<<<dim3(1), dim3(512), 0, stream>>>(bsum, bbase2);
  k_scanC<<<dim3(NBLK), B, 0, stream>>>(degi, bbase2, rowstart);
  k_bucket_b<<<dim3(NBUCK), B, 0, stream>>>(pairs, bbase, rowstart, csr_src);
  // layer 1
  k_gemm1<<<dim3(GGRID), B, 0, stream>>>(x, W1, dinv, bufA);
  k_agg64<<<dim3(NN / 4), B, 0, stream>>>(bufA, dinv, rowstart, degi, csr_src, bufB);
  // layer 2
  k_gemm2<<<dim3(GGRID), B, 0, stream>>>(bufB, W2, b1, dinv, bufA);
  k_agg32pool<<<dim3(NN / 8), B, 0, stream>>>(bufA, dinv, rowstart, degi, csr_src, batch, b2, sums);
  // finalize
  k_final<<<dim3((NG * CO + 255) / 256), B, 0, stream>>>(sums, counts, out);
}

// Round 14
// 280.385 us; speedup vs baseline: 1.1528x; 1.1528x over previous
//
#include <hip/hip_runtime.h>

#define NN 100000
#define NE 1250000
#define CIN 64
#define CH 64
#define CO 32
#define NG 128
#define NBLK ((NN + 255) / 256)    // 391 (node-grid for scans)
#define NBUCK 98                    // buckets of 1024 nodes: dst>>10 in [0,97]
#define BSHIFT 10
#define EPB 2048                    // edges per partition block
#define NBLKP ((NE + EPB - 1) / EPB) // 611
#define GGRID 2048                  // grid-stride GEMM grid

// ---------------- init: zero sums+bhist, per-graph counts (block 0) -----------
static __global__ void k_zero(float* __restrict__ sums, int* __restrict__ bhist,
                              const int* __restrict__ batch, float* __restrict__ counts) {
  int i = blockIdx.x * 256 + threadIdx.x;
  if (i < NG * CO) sums[i] = 0.0f;
  if (i < 128) bhist[i] = 0;
  if (blockIdx.x == 0 && threadIdx.x < NG) {
    int g = threadIdx.x;
    int lo = 0, hi = NN;
    while (lo < hi) { int m = (lo + hi) >> 1; if (batch[m] < g) lo = m + 1; else hi = m; }
    int lb = lo;
    lo = 0; hi = NN;
    while (lo < hi) { int m = (lo + hi) >> 1; if (batch[m] <= g) lo = m + 1; else hi = m; }
    counts[g] = (float)(lo - lb);
  }
}

// ---------------- bucket histogram (LDS-staged) ----------------
static __global__ __launch_bounds__(256) void k_bhist(const int* __restrict__ dst,
                                                      int* __restrict__ bhist) {
  __shared__ int lh[128];
  if (threadIdx.x < 128) lh[threadIdx.x] = 0;
  __syncthreads();
  int e0 = blockIdx.x * EPB, e1 = min(e0 + EPB, NE);
  for (int e = e0 + threadIdx.x; e < e1; e += 256)
    atomicAdd(&lh[dst[e] >> BSHIFT], 1);
  __syncthreads();
  if (threadIdx.x < 128) { int v = lh[threadIdx.x]; if (v) atomicAdd(&bhist[threadIdx.x], v); }
}

// ---------------- exclusive scan of bucket counts (1 block, 128 thr) ----------
static __global__ void k_bscan(const int* __restrict__ bhist, int* __restrict__ bbase,
                               int* __restrict__ bcursor) {
  __shared__ int tmp[128];
  int t = threadIdx.x;
  int v = bhist[t];
  tmp[t] = v;
  __syncthreads();
  for (int off = 1; off < 128; off <<= 1) {
    int a = (t >= off) ? tmp[t - off] : 0;
    __syncthreads();
    tmp[t] += a;
    __syncthreads();
  }
  int ex = tmp[t] - v;
  bbase[t] = ex;
  bcursor[t] = ex;
  if (t == 127) bbase[128] = tmp[127];  // == NE
}

// ------- partition edges into bucket-grouped (src,dst) pair runs --------------
static __global__ __launch_bounds__(256) void k_part(const int* __restrict__ src,
                                                     const int* __restrict__ dst,
                                                     int* __restrict__ bcursor,
                                                     int2* __restrict__ pairs) {
  __shared__ int lh[128], lbase[128], loff[128];
  if (threadIdx.x < 128) { lh[threadIdx.x] = 0; loff[threadIdx.x] = 0; }
  __syncthreads();
  int e0 = blockIdx.x * EPB, e1 = min(e0 + EPB, NE);
  for (int e = e0 + threadIdx.x; e < e1; e += 256)
    atomicAdd(&lh[dst[e] >> BSHIFT], 1);
  __syncthreads();
  if (threadIdx.x < 128) {
    int v = lh[threadIdx.x];
    lbase[threadIdx.x] = v ? atomicAdd(&bcursor[threadIdx.x], v) : 0;
  }
  __syncthreads();
  for (int e = e0 + threadIdx.x; e < e1; e += 256) {
    int d = dst[e], b = d >> BSHIFT;
    int o = atomicAdd(&loff[b], 1);
    pairs[lbase[b] + o] = make_int2(src[e], d);
  }
}

// ------- per-bucket degree via LDS histogram; coalesced degi/dinv writes ------
static __global__ __launch_bounds__(256) void k_bucket_a(const int2* __restrict__ pairs,
                                                         const int* __restrict__ bbase,
                                                         int* __restrict__ degi,
                                                         float* __restrict__ dinv) {
  __shared__ int lh[1024];
  for (int t = threadIdx.x; t < 1024; t += 256) lh[t] = 0;
  __syncthreads();
  int b = blockIdx.x;
  int p0 = bbase[b], p1 = bbase[b + 1];
  for (int p = p0 + threadIdx.x; p < p1; p += 256)
    atomicAdd(&lh[pairs[p].y & 1023], 1);
  __syncthreads();
  int nb = b << BSHIFT;
  for (int t = threadIdx.x; t < 1024; t += 256) {
    int node = nb + t;
    if (node < NN) { int dg = lh[t]; degi[node] = dg; dinv[node] = rsqrtf((float)dg + 1.0f); }
  }
}

// ---------------- prefix scan of degrees -> CSR row starts ----------------
static __global__ void k_scanA(const int* __restrict__ degi, int* __restrict__ bsum) {
  __shared__ int tmp[256];
  int i = blockIdx.x * 256 + threadIdx.x;
  int v = (i < NN) ? degi[i] : 0;
  tmp[threadIdx.x] = v;
  __syncthreads();
  for (int off = 128; off > 0; off >>= 1) {
    if (threadIdx.x < off) tmp[threadIdx.x] += tmp[threadIdx.x + off];
    __syncthreads();
  }
  if (threadIdx.x == 0) bsum[blockIdx.x] = tmp[0];
}

static __global__ void k_scanB(const int* __restrict__ bsum, int* __restrict__ bbase2) {
  __shared__ int tmp[512];
  int t = threadIdx.x;
  int v = (t < NBLK) ? bsum[t] : 0;
  tmp[t] = v;
  __syncthreads();
  for (int off = 1; off < 512; off <<= 1) {
    int add = (t >= off) ? tmp[t - off] : 0;
    __syncthreads();
    tmp[t] += add;
    __syncthreads();
  }
  if (t < NBLK) bbase2[t] = tmp[t] - v;  // exclusive
}

static __global__ void k_scanC(const int* __restrict__ degi, const int* __restrict__ bbase2,
                               int* __restrict__ rowstart) {
  __shared__ int tmp[256];
  int i = blockIdx.x * 256 + threadIdx.x;
  int v = (i < NN) ? degi[i] : 0;
  tmp[threadIdx.x] = v;
  __syncthreads();
  for (int off = 1; off < 256; off <<= 1) {
    int add = (threadIdx.x >= off) ? tmp[threadIdx.x - off] : 0;
    __syncthreads();
    tmp[threadIdx.x] += add;
    __syncthreads();
  }
  if (i < NN) rowstart[i] = bbase2[blockIdx.x] + tmp[threadIdx.x] - v;  // exclusive
}

// ------- per-bucket CSR scatter with LDS cursors (localized writes) -----------
static __global__ __launch_bounds__(256) void k_bucket_b(const int2* __restrict__ pairs,
                                                         const int* __restrict__ bbase,
                                                         const int* __restrict__ rowstart,
                                                         int* __restrict__ csr_src) {
  __shared__ int cur[1024];
  int b = blockIdx.x, nb = b << BSHIFT;
  for (int t = threadIdx.x; t < 1024; t += 256) {
    int node = nb + t;
    cur[t] = (node < NN) ? rowstart[node] : 0;
  }
  __syncthreads();
  int p0 = bbase[b], p1 = bbase[b + 1];
  for (int p = p0 + threadIdx.x; p < p1; p += 256) {
    int2 pr = pairs[p];
    int pos = atomicAdd(&cur[pr.y & 1023], 1);
    csr_src[pos] = pr.x;
  }
}

// -- GEMM 1: h' = dinv*(x @ W1); W column held in 64 REGISTERS per lane --------
static __global__ __launch_bounds__(256) void k_gemm1(const float* __restrict__ x,
                                                      const float* __restrict__ W,
                                                      const float* __restrict__ dinv,
                                                      float* __restrict__ h) {
  int wave = threadIdx.x >> 6;
  int lane = threadIdx.x & 63;
  float wr[CIN];
#pragma unroll
  for (int k = 0; k < CIN; ++k) wr[k] = W[k * CH + lane];  // coalesced, once
  for (int row = blockIdx.x * 4 + wave; row < NN; row += GGRID * 4) {
    const float4* xr = reinterpret_cast<const float4*>(x + row * CIN);
    float acc = 0.0f;
#pragma unroll
    for (int k4 = 0; k4 < CIN / 4; ++k4) {
      float4 xv = xr[k4];
      acc += xv.x * wr[k4 * 4 + 0];
      acc += xv.y * wr[k4 * 4 + 1];
      acc += xv.z * wr[k4 * 4 + 2];
      acc += xv.w * wr[k4 * 4 + 3];
    }
    h[row * CH + lane] = acc * dinv[row];
  }
}

// -- layer-1 agg + bias + relu fused: out = relu(dinv*(self+nbrs) + b1) --------
static __global__ __launch_bounds__(256) void k_agg64(const float* __restrict__ h,
                                                      const float* __restrict__ dinv,
                                                      const int* __restrict__ rowstart,
                                                      const int* __restrict__ degi,
                                                      const int* __restrict__ csr_src,
                                                      const float* __restrict__ b1,
                                                      float* __restrict__ agg) {
  int wave = threadIdx.x >> 6, lane = threadIdx.x & 63;
  int i = blockIdx.x * 4 + wave;  // grid exact: 25000*4
  float bias = b1[lane];
  float acc = h[i * CH + lane];   // self-loop (h already dinv-scaled)
  int s0 = rowstart[i], n = degi[i];
  int k = 0;
  for (; k + 3 < n; k += 4) {
    int sA = csr_src[s0 + k];
    int sB = csr_src[s0 + k + 1];
    int sC = csr_src[s0 + k + 2];
    int sD = csr_src[s0 + k + 3];
    float a = h[sA * CH + lane];
    float b = h[sB * CH + lane];
    float c = h[sC * CH + lane];
    float d = h[sD * CH + lane];
    acc += (a + b) + (c + d);
  }
  for (; k < n; ++k) acc += h[csr_src[s0 + k] * CH + lane];
  float v = acc * dinv[i] + bias;
  agg[i * CH + lane] = v > 0.0f ? v : 0.0f;
}

// -- GEMM 2: h2' = dinv*(aggRelu @ W2); W2 column in 64 registers --------------
static __global__ __launch_bounds__(256) void k_gemm2(const float* __restrict__ agg1,
                                                      const float* __restrict__ W,
                                                      const float* __restrict__ dinv,
                                                      float* __restrict__ h2) {
  int half = threadIdx.x >> 5;
  int j = threadIdx.x & 31;
  float wr[CH];
#pragma unroll
  for (int k = 0; k < CH; ++k) wr[k] = W[k * CO + j];  // coalesced, once
  for (int row = blockIdx.x * 8 + half; row < NN; row += GGRID * 8) {
    const float4* ar = reinterpret_cast<const float4*>(agg1 + row * CH);
    float acc = 0.0f;
#pragma unroll
    for (int k4 = 0; k4 < CH / 4; ++k4) {
      float4 av = ar[k4];
      acc += av.x * wr[k4 * 4 + 0];
      acc += av.y * wr[k4 * 4 + 1];
      acc += av.z * wr[k4 * 4 + 2];
      acc += av.w * wr[k4 * 4 + 3];
    }
    h2[row * CO + j] = acc * dinv[row];
  }
}

// ---- layer-2 agg + bias + mean-pool partial (LDS run-reduction) --------------
static __global__ __launch_bounds__(256) void k_agg32pool(const float* __restrict__ h2,
                                                          const float* __restrict__ dinv,
                                                          const int* __restrict__ rowstart,
                                                          const int* __restrict__ degi,
                                                          const int* __restrict__ csr_src,
                                                          const int* __restrict__ batch,
                                                          const float* __restrict__ b2,
                                                          float* __restrict__ sums) {
  __shared__ float vals[8][CO];
  __shared__ int gid[8];
  int half = threadIdx.x >> 5;  // 0..7 (node slot)
  int c = threadIdx.x & 31;
  int i = blockIdx.x * 8 + half;  // grid exact: 12500*8
  float acc = h2[i * CO + c];     // self-loop (h2 already dinv-scaled)
  int s0 = rowstart[i], n = degi[i];
  int k = 0;
  for (; k + 3 < n; k += 4) {
    int sA = csr_src[s0 + k];
    int sB = csr_src[s0 + k + 1];
    int sC = csr_src[s0 + k + 2];
    int sD = csr_src[s0 + k + 3];
    float a = h2[sA * CO + c];
    float b = h2[sB * CO + c];
    float cc = h2[sC * CO + c];
    float d = h2[sD * CO + c];
    acc += (a + b) + (cc + d);
  }
  for (; k < n; ++k) acc += h2[csr_src[s0 + k] * CO + c];
  vals[half][c] = acc * dinv[i] + b2[c];
  if (c == 0) gid[half] = batch[i];
  __syncthreads();
  if (threadIdx.x < 32) {
    int ch = threadIdx.x;
    float run = vals[0][ch];
    int g = gid[0];
    for (int s = 1; s < 8; ++s) {
      if (gid[s] == g) run += vals[s][ch];
      else { atomicAdd(&sums[g * CO + ch], run); g = gid[s]; run = vals[s][ch]; }
    }
    atomicAdd(&sums[g * CO + ch], run);
  }
}

static __global__ void k_final(const float* __restrict__ sums, const float* __restrict__ counts,
                               float* __restrict__ out) {
  int t = blockIdx.x * 256 + threadIdx.x;
  if (t >= NG * CO) return;
  out[t] = sums[t] / fmaxf(counts[t >> 5], 1.0f);
}

extern "C" void kernel_launch(void* const* d_in, const int* in_sizes, int n_in,
                              void* d_out, int out_size, void* d_ws, size_t ws_size,
                              hipStream_t stream) {
  const float* x   = (const float*)d_in[0];
  const int* ei    = (const int*)d_in[1];   // [2, NE]: src = ei, dst = ei+NE
  const int* batch = (const int*)d_in[2];
  const float* W1  = (const float*)d_in[3];
  const float* b1  = (const float*)d_in[4];
  const float* W2  = (const float*)d_in[5];
  const float* b2  = (const float*)d_in[6];
  float* out = (float*)d_out;

  const int* src = ei;
  const int* dst = ei + NE;

  char* base = (char*)d_ws;
  size_t off = 0;
  auto alloc = [&](size_t nelem) {
    void* p = (void*)(base + off);
    off += ((nelem * 4 + 255) / 256) * 256;
    return p;
  };
  int* degi      = (int*)alloc(NN);
  int* rowstart  = (int*)alloc(NN);
  float* dinv    = (float*)alloc(NN);
  int* bsum      = (int*)alloc(NBLK);
  int* bbase2    = (int*)alloc(NBLK);
  int* bhist     = (int*)alloc(128);
  int* bbase     = (int*)alloc(129);
  int* bcursor   = (int*)alloc(128);
  int* csr_src   = (int*)alloc(NE);                 // 5 MB
  float* bufA    = (float*)alloc((size_t)NN * CH);  // h1' then h2'
  float* bufB    = (float*)alloc((size_t)NN * CH);  // pairs (10 MB) then agg1
  float* sums    = (float*)alloc(NG * CO);
  float* counts  = (float*)alloc(NG);
  int2* pairs    = (int2*)bufB;  // dead once k_bucket_b finishes; agg64 then owns bufB

  dim3 B(256);
  // CSR build (bucketed, cache-friendly)
  k_zero<<<dim3(16), B, 0, stream>>>(sums, bhist, batch, counts);
  k_bhist<<<dim3(NBLKP), B, 0, stream>>>(dst, bhist);
  k_bscan<<<dim3(1), dim3(128), 0, stream>>>(bhist, bbase, bcursor);
  k_part<<<dim3(NBLKP), B, 0, stream>>>(src, dst, bcursor, pairs);
  k_bucket_a<<<dim3(NBUCK), B, 0, stream>>>(pairs, bbase, degi, dinv);
  k_scanA<<<dim3(NBLK), B, 0, stream>>>(degi, bsum);
  k_scanB<<<dim3(1), dim3(512), 0, stream>>>(bsum, bbase2);
  k_scanC<<<dim3(NBLK), B, 0, stream>>>(degi, bbase2, rowstart);
  k_bucket_b<<<dim3(NBUCK), B, 0, stream>>>(pairs, bbase, rowstart, csr_src);
  // layer 1
  k_gemm1<<<dim3(GGRID), B, 0, stream>>>(x, W1, dinv, bufA);
  k_agg64<<<dim3(NN / 4), B, 0, stream>>>(bufA, dinv, rowstart, degi, csr_src, b1, bufB);
  // layer 2 (bias+relu fused into agg64's write)
  k_gemm2<<<dim3(GGRID), B, 0, stream>>>(bufB, W2, dinv, bufA);
  k_agg32pool<<<dim3(NN / 8), B, 0, stream>>>(bufA, dinv, rowstart, degi, csr_src, batch, b2, sums);
  // finalize
  k_final<<<dim3((NG * CO + 255) / 256), B, 0, stream>>>(sums, counts, out);
}

// Round 15
// 255.912 us; speedup vs baseline: 1.2631x; 1.0956x over previous
//
#include <hip/hip_runtime.h>

#define NN 100000
#define NE 1250000
#define CIN 64
#define CH 64
#define CO 32
#define NG 128
#define NBLK ((NN + 255) / 256)    // 391 (node-grid for scans)
#define NBUCK 98                    // buckets of 1024 nodes: dst>>10 in [0,97]
#define BSHIFT 10
#define EPB 2048                    // edges per partition block
#define NBLKP ((NE + EPB - 1) / EPB) // 611
#define GGRID 2048                  // grid-stride GEMM grid

// ---------------- init: zero sums+bhist, per-graph counts (block 0) -----------
static __global__ void k_zero(float* __restrict__ sums, int* __restrict__ bhist,
                              const int* __restrict__ batch, float* __restrict__ counts) {
  int i = blockIdx.x * 256 + threadIdx.x;
  if (i < NG * CO) sums[i] = 0.0f;
  if (i < 128) bhist[i] = 0;
  if (blockIdx.x == 0 && threadIdx.x < NG) {
    int g = threadIdx.x;
    int lo = 0, hi = NN;
    while (lo < hi) { int m = (lo + hi) >> 1; if (batch[m] < g) lo = m + 1; else hi = m; }
    int lb = lo;
    lo = 0; hi = NN;
    while (lo < hi) { int m = (lo + hi) >> 1; if (batch[m] <= g) lo = m + 1; else hi = m; }
    counts[g] = (float)(lo - lb);
  }
}

// ---------------- bucket histogram (LDS-staged) ----------------
static __global__ __launch_bounds__(256) void k_bhist(const int* __restrict__ dst,
                                                      int* __restrict__ bhist) {
  __shared__ int lh[128];
  if (threadIdx.x < 128) lh[threadIdx.x] = 0;
  __syncthreads();
  int e0 = blockIdx.x * EPB, e1 = min(e0 + EPB, NE);
  for (int e = e0 + threadIdx.x; e < e1; e += 256)
    atomicAdd(&lh[dst[e] >> BSHIFT], 1);
  __syncthreads();
  if (threadIdx.x < 128) { int v = lh[threadIdx.x]; if (v) atomicAdd(&bhist[threadIdx.x], v); }
}

// ---------------- exclusive scan of bucket counts (1 block, 128 thr) ----------
static __global__ void k_bscan(const int* __restrict__ bhist, int* __restrict__ bbase,
                               int* __restrict__ bcursor) {
  __shared__ int tmp[128];
  int t = threadIdx.x;
  int v = bhist[t];
  tmp[t] = v;
  __syncthreads();
  for (int off = 1; off < 128; off <<= 1) {
    int a = (t >= off) ? tmp[t - off] : 0;
    __syncthreads();
    tmp[t] += a;
    __syncthreads();
  }
  int ex = tmp[t] - v;
  bbase[t] = ex;
  bcursor[t] = ex;
  if (t == 127) bbase[128] = tmp[127];  // == NE
}

// ------- partition edges into bucket-grouped (src,dst) pair runs --------------
static __global__ __launch_bounds__(256) void k_part(const int* __restrict__ src,
                                                     const int* __restrict__ dst,
                                                     int* __restrict__ bcursor,
                                                     int2* __restrict__ pairs) {
  __shared__ int lh[128], lbase[128], loff[128];
  if (threadIdx.x < 128) { lh[threadIdx.x] = 0; loff[threadIdx.x] = 0; }
  __syncthreads();
  int e0 = blockIdx.x * EPB, e1 = min(e0 + EPB, NE);
  for (int e = e0 + threadIdx.x; e < e1; e += 256)
    atomicAdd(&lh[dst[e] >> BSHIFT], 1);
  __syncthreads();
  if (threadIdx.x < 128) {
    int v = lh[threadIdx.x];
    lbase[threadIdx.x] = v ? atomicAdd(&bcursor[threadIdx.x], v) : 0;
  }
  __syncthreads();
  for (int e = e0 + threadIdx.x; e < e1; e += 256) {
    int d = dst[e], b = d >> BSHIFT;
    int o = atomicAdd(&loff[b], 1);
    pairs[lbase[b] + o] = make_int2(src[e], d);
  }
}

// ------- per-bucket degree via LDS histogram; coalesced degi/dinv writes ------
static __global__ __launch_bounds__(256) void k_bucket_a(const int2* __restrict__ pairs,
                                                         const int* __restrict__ bbase,
                                                         int* __restrict__ degi,
                                                         float* __restrict__ dinv) {
  __shared__ int lh[1024];
  for (int t = threadIdx.x; t < 1024; t += 256) lh[t] = 0;
  __syncthreads();
  int b = blockIdx.x;
  int p0 = bbase[b], p1 = bbase[b + 1];
  for (int p = p0 + threadIdx.x; p < p1; p += 256)
    atomicAdd(&lh[pairs[p].y & 1023], 1);
  __syncthreads();
  int nb = b << BSHIFT;
  for (int t = threadIdx.x; t < 1024; t += 256) {
    int node = nb + t;
    if (node < NN) { int dg = lh[t]; degi[node] = dg; dinv[node] = rsqrtf((float)dg + 1.0f); }
  }
}

// ---------------- prefix scan of degrees -> CSR row starts ----------------
static __global__ void k_scanA(const int* __restrict__ degi, int* __restrict__ bsum) {
  __shared__ int tmp[256];
  int i = blockIdx.x * 256 + threadIdx.x;
  int v = (i < NN) ? degi[i] : 0;
  tmp[threadIdx.x] = v;
  __syncthreads();
  for (int off = 128; off > 0; off >>= 1) {
    if (threadIdx.x < off) tmp[threadIdx.x] += tmp[threadIdx.x + off];
    __syncthreads();
  }
  if (threadIdx.x == 0) bsum[blockIdx.x] = tmp[0];
}

static __global__ void k_scanB(const int* __restrict__ bsum, int* __restrict__ bbase2) {
  __shared__ int tmp[512];
  int t = threadIdx.x;
  int v = (t < NBLK) ? bsum[t] : 0;
  tmp[t] = v;
  __syncthreads();
  for (int off = 1; off < 512; off <<= 1) {
    int add = (t >= off) ? tmp[t - off] : 0;
    __syncthreads();
    tmp[t] += add;
    __syncthreads();
  }
  if (t < NBLK) bbase2[t] = tmp[t] - v;  // exclusive
}

static __global__ void k_scanC(const int* __restrict__ degi, const int* __restrict__ bbase2,
                               int* __restrict__ rowstart) {
  __shared__ int tmp[256];
  int i = blockIdx.x * 256 + threadIdx.x;
  int v = (i < NN) ? degi[i] : 0;
  tmp[threadIdx.x] = v;
  __syncthreads();
  for (int off = 1; off < 256; off <<= 1) {
    int add = (threadIdx.x >= off) ? tmp[threadIdx.x - off] : 0;
    __syncthreads();
    tmp[threadIdx.x] += add;
    __syncthreads();
  }
  if (i < NN) rowstart[i] = bbase2[blockIdx.x] + tmp[threadIdx.x] - v;  // exclusive
}

// ------- per-bucket CSR scatter with LDS cursors (localized writes) -----------
static __global__ __launch_bounds__(256) void k_bucket_b(const int2* __restrict__ pairs,
                                                         const int* __restrict__ bbase,
                                                         const int* __restrict__ rowstart,
                                                         int* __restrict__ csr_src) {
  __shared__ int cur[1024];
  int b = blockIdx.x, nb = b << BSHIFT;
  for (int t = threadIdx.x; t < 1024; t += 256) {
    int node = nb + t;
    cur[t] = (node < NN) ? rowstart[node] : 0;
  }
  __syncthreads();
  int p0 = bbase[b], p1 = bbase[b + 1];
  for (int p = p0 + threadIdx.x; p < p1; p += 256) {
    int2 pr = pairs[p];
    int pos = atomicAdd(&cur[pr.y & 1023], 1);
    csr_src[pos] = pr.x;
  }
}

// -- GEMM 1: h' = dinv*(x @ W1); W col in regs; x row via SCALAR loads ---------
static __global__ __launch_bounds__(256) void k_gemm1(const float* __restrict__ x,
                                                      const float* __restrict__ W,
                                                      const float* __restrict__ dinv,
                                                      float* __restrict__ h) {
  int wave = threadIdx.x >> 6;
  int lane = threadIdx.x & 63;
  float wr[CIN];
#pragma unroll
  for (int k = 0; k < CIN; ++k) wr[k] = W[k * CH + lane];  // coalesced, once
  for (int row0 = blockIdx.x * 4 + wave; row0 < NN; row0 += GGRID * 4) {
    // row is identical across the wave's 64 lanes; make it explicit so the
    // compiler emits s_load (SMEM) for the x row instead of broadcast VMEM.
    int row = __builtin_amdgcn_readfirstlane(row0);
    const float4* xr = reinterpret_cast<const float4*>(x + (size_t)row * CIN);
    float dv = dinv[row];  // uniform -> scalar load
    float a0 = 0.f, a1 = 0.f, a2 = 0.f, a3 = 0.f;  // break the dep chain
#pragma unroll
    for (int k4 = 0; k4 < CIN / 4; k4 += 4) {
      float4 v0 = xr[k4 + 0];
      float4 v1 = xr[k4 + 1];
      float4 v2 = xr[k4 + 2];
      float4 v3 = xr[k4 + 3];
      a0 += v0.x * wr[4 * k4 + 0] + v0.y * wr[4 * k4 + 1] + v0.z * wr[4 * k4 + 2] + v0.w * wr[4 * k4 + 3];
      a1 += v1.x * wr[4 * k4 + 4] + v1.y * wr[4 * k4 + 5] + v1.z * wr[4 * k4 + 6] + v1.w * wr[4 * k4 + 7];
      a2 += v2.x * wr[4 * k4 + 8] + v2.y * wr[4 * k4 + 9] + v2.z * wr[4 * k4 + 10] + v2.w * wr[4 * k4 + 11];
      a3 += v3.x * wr[4 * k4 + 12] + v3.y * wr[4 * k4 + 13] + v3.z * wr[4 * k4 + 14] + v3.w * wr[4 * k4 + 15];
    }
    h[(size_t)row * CH + lane] = ((a0 + a1) + (a2 + a3)) * dv;
  }
}

// -- layer-1 agg + bias + relu fused: out = relu(dinv*(self+nbrs) + b1) --------
static __global__ __launch_bounds__(256) void k_agg64(const float* __restrict__ h,
                                                      const float* __restrict__ dinv,
                                                      const int* __restrict__ rowstart,
                                                      const int* __restrict__ degi,
                                                      const int* __restrict__ csr_src,
                                                      const float* __restrict__ b1,
                                                      float* __restrict__ agg) {
  int wave = threadIdx.x >> 6, lane = threadIdx.x & 63;
  int i = blockIdx.x * 4 + wave;  // grid exact: 25000*4
  float bias = b1[lane];
  float acc = h[i * CH + lane];   // self-loop (h already dinv-scaled)
  int s0 = rowstart[i], n = degi[i];
  int k = 0;
  for (; k + 3 < n; k += 4) {
    int sA = csr_src[s0 + k];
    int sB = csr_src[s0 + k + 1];
    int sC = csr_src[s0 + k + 2];
    int sD = csr_src[s0 + k + 3];
    float a = h[sA * CH + lane];
    float b = h[sB * CH + lane];
    float c = h[sC * CH + lane];
    float d = h[sD * CH + lane];
    acc += (a + b) + (c + d);
  }
  for (; k < n; ++k) acc += h[csr_src[s0 + k] * CH + lane];
  float v = acc * dinv[i] + bias;
  agg[i * CH + lane] = v > 0.0f ? v : 0.0f;
}

// -- GEMM 2: h2' = dinv*(aggRelu @ W2); W2 column in 64 registers --------------
static __global__ __launch_bounds__(256) void k_gemm2(const float* __restrict__ agg1,
                                                      const float* __restrict__ W,
                                                      const float* __restrict__ dinv,
                                                      float* __restrict__ h2) {
  int half = threadIdx.x >> 5;
  int j = threadIdx.x & 31;
  float wr[CH];
#pragma unroll
  for (int k = 0; k < CH; ++k) wr[k] = W[k * CO + j];  // coalesced, once
  for (int row = blockIdx.x * 8 + half; row < NN; row += GGRID * 8) {
    const float4* ar = reinterpret_cast<const float4*>(agg1 + row * CH);
    float acc = 0.0f;
#pragma unroll
    for (int k4 = 0; k4 < CH / 4; ++k4) {
      float4 av = ar[k4];
      acc += av.x * wr[k4 * 4 + 0];
      acc += av.y * wr[k4 * 4 + 1];
      acc += av.z * wr[k4 * 4 + 2];
      acc += av.w * wr[k4 * 4 + 3];
    }
    h2[row * CO + j] = acc * dinv[row];
  }
}

// ---- layer-2 agg + bias + mean-pool partial (LDS run-reduction) --------------
static __global__ __launch_bounds__(256) void k_agg32pool(const float* __restrict__ h2,
                                                          const float* __restrict__ dinv,
                                                          const int* __restrict__ rowstart,
                                                          const int* __restrict__ degi,
                                                          const int* __restrict__ csr_src,
                                                          const int* __restrict__ batch,
                                                          const float* __restrict__ b2,
                                                          float* __restrict__ sums) {
  __shared__ float vals[8][CO];
  __shared__ int gid[8];
  int half = threadIdx.x >> 5;  // 0..7 (node slot)
  int c = threadIdx.x & 31;
  int i = blockIdx.x * 8 + half;  // grid exact: 12500*8
  float acc = h2[i * CO + c];     // self-loop (h2 already dinv-scaled)
  int s0 = rowstart[i], n = degi[i];
  int k = 0;
  for (; k + 3 < n; k += 4) {
    int sA = csr_src[s0 + k];
    int sB = csr_src[s0 + k + 1];
    int sC = csr_src[s0 + k + 2];
    int sD = csr_src[s0 + k + 3];
    float a = h2[sA * CO + c];
    float b = h2[sB * CO + c];
    float cc = h2[sC * CO + c];
    float d = h2[sD * CO + c];
    acc += (a + b) + (cc + d);
  }
  for (; k < n; ++k) acc += h2[csr_src[s0 + k] * CO + c];
  vals[half][c] = acc * dinv[i] + b2[c];
  if (c == 0) gid[half] = batch[i];
  __syncthreads();
  if (threadIdx.x < 32) {
    int ch = threadIdx.x;
    float run = vals[0][ch];
    int g = gid[0];
    for (int s = 1; s < 8; ++s) {
      if (gid[s] == g) run += vals[s][ch];
      else { atomicAdd(&sums[g * CO + ch], run); g = gid[s]; run = vals[s][ch]; }
    }
    atomicAdd(&sums[g * CO + ch], run);
  }
}

static __global__ void k_final(const float* __restrict__ sums, const float* __restrict__ counts,
                               float* __restrict__ out) {
  int t = blockIdx.x * 256 + threadIdx.x;
  if (t >= NG * CO) return;
  out[t] = sums[t] / fmaxf(counts[t >> 5], 1.0f);
}

extern "C" void kernel_launch(void* const* d_in, const int* in_sizes, int n_in,
                              void* d_out, int out_size, void* d_ws, size_t ws_size,
                              hipStream_t stream) {
  const float* x   = (const float*)d_in[0];
  const int* ei    = (const int*)d_in[1];   // [2, NE]: src = ei, dst = ei+NE
  const int* batch = (const int*)d_in[2];
  const float* W1  = (const float*)d_in[3];
  const float* b1  = (const float*)d_in[4];
  const float* W2  = (const float*)d_in[5];
  const float* b2  = (const float*)d_in[6];
  float* out = (float*)d_out;

  const int* src = ei;
  const int* dst = ei + NE;

  char* base = (char*)d_ws;
  size_t off = 0;
  auto alloc = [&](size_t nelem) {
    void* p = (void*)(base + off);
    off += ((nelem * 4 + 255) / 256) * 256;
    return p;
  };
  int* degi      = (int*)alloc(NN);
  int* rowstart  = (int*)alloc(NN);
  float* dinv    = (float*)alloc(NN);
  int* bsum      = (int*)alloc(NBLK);
  int* bbase2    = (int*)alloc(NBLK);
  int* bhist     = (int*)alloc(128);
  int* bbase     = (int*)alloc(129);
  int* bcursor   = (int*)alloc(128);
  int* csr_src   = (int*)alloc(NE);                 // 5 MB
  float* bufA    = (float*)alloc((size_t)NN * CH);  // h1' then h2'
  float* bufB    = (float*)alloc((size_t)NN * CH);  // pairs (10 MB) then agg1
  float* sums    = (float*)alloc(NG * CO);
  float* counts  = (float*)alloc(NG);
  int2* pairs    = (int2*)bufB;  // dead once k_bucket_b finishes; agg64 then owns bufB

  dim3 B(256);
  // CSR build (bucketed, cache-friendly)
  k_zero<<<dim3(16), B, 0, stream>>>(sums, bhist, batch, counts);
  k_bhist<<<dim3(NBLKP), B, 0, stream>>>(dst, bhist);
  k_bscan<<<dim3(1), dim3(128), 0, stream>>>(bhist, bbase, bcursor);
  k_part<<<dim3(NBLKP), B, 0, stream>>>(src, dst, bcursor, pairs);
  k_bucket_a<<<dim3(NBUCK), B, 0, stream>>>(pairs, bbase, degi, dinv);
  k_scanA<<<dim3(NBLK), B, 0, stream>>>(degi, bsum);
  k_scanB<<<dim3(1), dim3(512), 0, stream>>>(bsum, bbase2);
  k_scanC<<<dim3(NBLK), B, 0, stream>>>(degi, bbase2, rowstart);
  k_bucket_b<<<dim3(NBUCK), B, 0, stream>>>(pairs, bbase, rowstart, csr_src);
  // layer 1
  k_gemm1<<<dim3(GGRID), B, 0, stream>>>(x, W1, dinv, bufA);
  k_agg64<<<dim3(NN / 4), B, 0, stream>>>(bufA, dinv, rowstart, degi, csr_src, b1, bufB);
  // layer 2 (bias+relu fused into agg64's write)
  k_gemm2<<<dim3(GGRID), B, 0, stream>>>(bufB, W2, dinv, bufA);
  k_agg32pool<<<dim3(NN / 8), B, 0, stream>>>(bufA, dinv, rowstart, degi, csr_src, batch, b2, sums);
  // finalize
  k_final<<<dim3((NG * CO + 255) / 256), B, 0, stream>>>(sums, counts, out);
}

// Round 17
// 253.264 us; speedup vs baseline: 1.2763x; 1.0105x over previous
//
#include <hip/hip_runtime.h>

#define NN 100000
#define NE 1250000
#define CIN 64
#define CH 64
#define CO 32
#define NG 128
#define NBLK ((NN + 255) / 256)    // 391 (node-grid for scans)
#define NBUCK 98                    // buckets of 1024 nodes: dst>>10 in [0,97]
#define BSHIFT 10
#define EPB 2048                    // edges per partition block
#define NBLKP ((NE + EPB - 1) / EPB) // 611
#define GGRID 2048                  // grid-stride GEMM grid

typedef unsigned short ushortT;

static __device__ inline ushortT f2bf(float v) {
  unsigned int u = __float_as_uint(v);
  u += 0x7FFFu + ((u >> 16) & 1u);   // round-to-nearest-even
  return (ushortT)(u >> 16);
}
static __device__ inline float bf2f(ushortT s) {
  return __uint_as_float(((unsigned int)s) << 16);
}

// ---------------- init: zero sums+bhist, per-graph counts (block 0) -----------
static __global__ void k_zero(float* __restrict__ sums, int* __restrict__ bhist,
                              const int* __restrict__ batch, float* __restrict__ counts) {
  int i = blockIdx.x * 256 + threadIdx.x;
  if (i < NG * CO) sums[i] = 0.0f;
  if (i < 128) bhist[i] = 0;
  if (blockIdx.x == 0 && threadIdx.x < NG) {
    int g = threadIdx.x;
    int lo = 0, hi = NN;
    while (lo < hi) { int m = (lo + hi) >> 1; if (batch[m] < g) lo = m + 1; else hi = m; }
    int lb = lo;
    lo = 0; hi = NN;
    while (lo < hi) { int m = (lo + hi) >> 1; if (batch[m] <= g) lo = m + 1; else hi = m; }
    counts[g] = (float)(lo - lb);
  }
}

// ---------------- bucket histogram (LDS-staged) ----------------
static __global__ __launch_bounds__(256) void k_bhist(const int* __restrict__ dst,
                                                      int* __restrict__ bhist) {
  __shared__ int lh[128];
  if (threadIdx.x < 128) lh[threadIdx.x] = 0;
  __syncthreads();
  int e0 = blockIdx.x * EPB, e1 = min(e0 + EPB, NE);
  for (int e = e0 + threadIdx.x; e < e1; e += 256)
    atomicAdd(&lh[dst[e] >> BSHIFT], 1);
  __syncthreads();
  if (threadIdx.x < 128) { int v = lh[threadIdx.x]; if (v) atomicAdd(&bhist[threadIdx.x], v); }
}

// ---------------- exclusive scan of bucket counts (1 block, 128 thr) ----------
static __global__ void k_bscan(const int* __restrict__ bhist, int* __restrict__ bbase,
                               int* __restrict__ bcursor) {
  __shared__ int tmp[128];
  int t = threadIdx.x;
  int v = bhist[t];
  tmp[t] = v;
  __syncthreads();
  for (int off = 1; off < 128; off <<= 1) {
    int a = (t >= off) ? tmp[t - off] : 0;
    __syncthreads();
    tmp[t] += a;
    __syncthreads();
  }
  int ex = tmp[t] - v;
  bbase[t] = ex;
  bcursor[t] = ex;
  if (t == 127) bbase[128] = tmp[127];  // == NE
}

// -- partition edges into bucket-grouped packed runs: pk = src | (d&1023)<<17 --
static __global__ __launch_bounds__(256) void k_part(const int* __restrict__ src,
                                                     const int* __restrict__ dst,
                                                     int* __restrict__ bcursor,
                                                     unsigned int* __restrict__ pairs) {
  __shared__ int lh[128], lbase[128], loff[128];
  if (threadIdx.x < 128) { lh[threadIdx.x] = 0; loff[threadIdx.x] = 0; }
  __syncthreads();
  int e0 = blockIdx.x * EPB, e1 = min(e0 + EPB, NE);
  for (int e = e0 + threadIdx.x; e < e1; e += 256)
    atomicAdd(&lh[dst[e] >> BSHIFT], 1);
  __syncthreads();
  if (threadIdx.x < 128) {
    int v = lh[threadIdx.x];
    lbase[threadIdx.x] = v ? atomicAdd(&bcursor[threadIdx.x], v) : 0;
  }
  __syncthreads();
  for (int e = e0 + threadIdx.x; e < e1; e += 256) {
    int d = dst[e], b = d >> BSHIFT;
    int o = atomicAdd(&loff[b], 1);
    pairs[lbase[b] + o] = (unsigned int)src[e] | ((unsigned int)(d & 1023) << 17);
  }
}

// ------- per-bucket degree via LDS histogram; coalesced degi/dinv writes ------
static __global__ __launch_bounds__(256) void k_bucket_a(const unsigned int* __restrict__ pairs,
                                                         const int* __restrict__ bbase,
                                                         int* __restrict__ degi,
                                                         float* __restrict__ dinv) {
  __shared__ int lh[1024];
  for (int t = threadIdx.x; t < 1024; t += 256) lh[t] = 0;
  __syncthreads();
  int b = blockIdx.x;
  int p0 = bbase[b], p1 = bbase[b + 1];
  for (int p = p0 + threadIdx.x; p < p1; p += 256)
    atomicAdd(&lh[pairs[p] >> 17], 1);
  __syncthreads();
  int nb = b << BSHIFT;
  for (int t = threadIdx.x; t < 1024; t += 256) {
    int node = nb + t;
    if (node < NN) { int dg = lh[t]; degi[node] = dg; dinv[node] = rsqrtf((float)dg + 1.0f); }
  }
}

// ---------------- prefix scan of degrees -> CSR row starts ----------------
static __global__ void k_scanA(const int* __restrict__ degi, int* __restrict__ bsum) {
  __shared__ int tmp[256];
  int i = blockIdx.x * 256 + threadIdx.x;
  int v = (i < NN) ? degi[i] : 0;
  tmp[threadIdx.x] = v;
  __syncthreads();
  for (int off = 128; off > 0; off >>= 1) {
    if (threadIdx.x < off) tmp[threadIdx.x] += tmp[threadIdx.x + off];
    __syncthreads();
  }
  if (threadIdx.x == 0) bsum[blockIdx.x] = tmp[0];
}

static __global__ void k_scanB(const int* __restrict__ bsum, int* __restrict__ bbase2) {
  __shared__ int tmp[512];
  int t = threadIdx.x;
  int v = (t < NBLK) ? bsum[t] : 0;
  tmp[t] = v;
  __syncthreads();
  for (int off = 1; off < 512; off <<= 1) {
    int add = (t >= off) ? tmp[t - off] : 0;
    __syncthreads();
    tmp[t] += add;
    __syncthreads();
  }
  if (t < NBLK) bbase2[t] = tmp[t] - v;  // exclusive
}

static __global__ void k_scanC(const int* __restrict__ degi, const int* __restrict__ bbase2,
                               int* __restrict__ rowstart) {
  __shared__ int tmp[256];
  int i = blockIdx.x * 256 + threadIdx.x;
  int v = (i < NN) ? degi[i] : 0;
  tmp[threadIdx.x] = v;
  __syncthreads();
  for (int off = 1; off < 256; off <<= 1) {
    int add = (threadIdx.x >= off) ? tmp[threadIdx.x - off] : 0;
    __syncthreads();
    tmp[threadIdx.x] += add;
    __syncthreads();
  }
  if (i < NN) rowstart[i] = bbase2[blockIdx.x] + tmp[threadIdx.x] - v;  // exclusive
}

// ------- per-bucket CSR scatter with LDS cursors (localized writes) -----------
static __global__ __launch_bounds__(256) void k_bucket_b(const unsigned int* __restrict__ pairs,
                                                         const int* __restrict__ bbase,
                                                         const int* __restrict__ rowstart,
                                                         int* __restrict__ csr_src) {
  __shared__ int cur[1024];
  int b = blockIdx.x, nb = b << BSHIFT;
  for (int t = threadIdx.x; t < 1024; t += 256) {
    int node = nb + t;
    cur[t] = (node < NN) ? rowstart[node] : 0;
  }
  __syncthreads();
  int p0 = bbase[b], p1 = bbase[b + 1];
  for (int p = p0 + threadIdx.x; p < p1; p += 256) {
    unsigned int pk = pairs[p];
    int pos = atomicAdd(&cur[pk >> 17], 1);
    csr_src[pos] = (int)(pk & 0x1FFFFu);
  }
}

// -- GEMM 1: h' = bf16(dinv*(x @ W1)); W col in regs; x row via SCALAR loads ---
static __global__ __launch_bounds__(256) void k_gemm1(const float* __restrict__ x,
                                                      const float* __restrict__ W,
                                                      const float* __restrict__ dinv,
                                                      ushortT* __restrict__ h) {
  int wave = threadIdx.x >> 6;
  int lane = threadIdx.x & 63;
  float wr[CIN];
#pragma unroll
  for (int k = 0; k < CIN; ++k) wr[k] = W[k * CH + lane];  // coalesced, once
  for (int row0 = blockIdx.x * 4 + wave; row0 < NN; row0 += GGRID * 4) {
    int row = __builtin_amdgcn_readfirstlane(row0);
    const float4* xr = reinterpret_cast<const float4*>(x + (size_t)row * CIN);
    float dv = dinv[row];  // uniform -> scalar load
    float a0 = 0.f, a1 = 0.f, a2 = 0.f, a3 = 0.f;
#pragma unroll
    for (int k4 = 0; k4 < CIN / 4; k4 += 4) {
      float4 v0 = xr[k4 + 0];
      float4 v1 = xr[k4 + 1];
      float4 v2 = xr[k4 + 2];
      float4 v3 = xr[k4 + 3];
      a0 += v0.x * wr[4 * k4 + 0] + v0.y * wr[4 * k4 + 1] + v0.z * wr[4 * k4 + 2] + v0.w * wr[4 * k4 + 3];
      a1 += v1.x * wr[4 * k4 + 4] + v1.y * wr[4 * k4 + 5] + v1.z * wr[4 * k4 + 6] + v1.w * wr[4 * k4 + 7];
      a2 += v2.x * wr[4 * k4 + 8] + v2.y * wr[4 * k4 + 9] + v2.z * wr[4 * k4 + 10] + v2.w * wr[4 * k4 + 11];
      a3 += v3.x * wr[4 * k4 + 12] + v3.y * wr[4 * k4 + 13] + v3.z * wr[4 * k4 + 14] + v3.w * wr[4 * k4 + 15];
    }
    h[(size_t)row * CH + lane] = f2bf(((a0 + a1) + (a2 + a3)) * dv);
  }
}

// -- layer-1 agg (bf16 gather) + bias + relu: out = relu(dinv*(self+nbrs)+b1) --
static __global__ __launch_bounds__(256) void k_agg64(const ushortT* __restrict__ h,
                                                      const float* __restrict__ dinv,
                                                      const int* __restrict__ rowstart,
                                                      const int* __restrict__ degi,
                                                      const int* __restrict__ csr_src,
                                                      const float* __restrict__ b1,
                                                      float* __restrict__ agg) {
  int wave = threadIdx.x >> 6, lane = threadIdx.x & 63;
  int i = blockIdx.x * 4 + wave;  // grid exact: 25000*4
  float bias = b1[lane];
  float acc = bf2f(h[(size_t)i * CH + lane]);   // self-loop (h already dinv-scaled)
  int s0 = rowstart[i], n = degi[i];
  int k = 0;
  for (; k + 3 < n; k += 4) {
    int sA = csr_src[s0 + k];
    int sB = csr_src[s0 + k + 1];
    int sC = csr_src[s0 + k + 2];
    int sD = csr_src[s0 + k + 3];
    float a = bf2f(h[(size_t)sA * CH + lane]);
    float b = bf2f(h[(size_t)sB * CH + lane]);
    float c = bf2f(h[(size_t)sC * CH + lane]);
    float d = bf2f(h[(size_t)sD * CH + lane]);
    acc += (a + b) + (c + d);
  }
  for (; k < n; ++k) acc += bf2f(h[(size_t)csr_src[s0 + k] * CH + lane]);
  float v = acc * dinv[i] + bias;
  agg[(size_t)i * CH + lane] = v > 0.0f ? v : 0.0f;
}

// -- GEMM 2: h2' = bf16(dinv*(aggRelu @ W2)); W2 column in 64 registers --------
static __global__ __launch_bounds__(256) void k_gemm2(const float* __restrict__ agg1,
                                                      const float* __restrict__ W,
                                                      const float* __restrict__ dinv,
                                                      ushortT* __restrict__ h2) {
  int half = threadIdx.x >> 5;
  int j = threadIdx.x & 31;
  float wr[CH];
#pragma unroll
  for (int k = 0; k < CH; ++k) wr[k] = W[k * CO + j];  // coalesced, once
  for (int row = blockIdx.x * 8 + half; row < NN; row += GGRID * 8) {
    const float4* ar = reinterpret_cast<const float4*>(agg1 + (size_t)row * CH);
    float acc = 0.0f;
#pragma unroll
    for (int k4 = 0; k4 < CH / 4; ++k4) {
      float4 av = ar[k4];
      acc += av.x * wr[k4 * 4 + 0];
      acc += av.y * wr[k4 * 4 + 1];
      acc += av.z * wr[k4 * 4 + 2];
      acc += av.w * wr[k4 * 4 + 3];
    }
    h2[(size_t)row * CO + j] = f2bf(acc * dinv[row]);
  }
}

// ---- layer-2 agg (bf16 gather) + bias + mean-pool partial (LDS reduction) ----
static __global__ __launch_bounds__(256) void k_agg32pool(const ushortT* __restrict__ h2,
                                                          const float* __restrict__ dinv,
                                                          const int* __restrict__ rowstart,
                                                          const int* __restrict__ degi,
                                                          const int* __restrict__ csr_src,
                                                          const int* __restrict__ batch,
                                                          const float* __restrict__ b2,
                                                          float* __restrict__ sums) {
  __shared__ float vals[8][CO];
  __shared__ int gid[8];
  int half = threadIdx.x >> 5;  // 0..7 (node slot)
  int c = threadIdx.x & 31;
  int i = blockIdx.x * 8 + half;  // grid exact: 12500*8
  float acc = bf2f(h2[(size_t)i * CO + c]);     // self-loop (h2 already dinv-scaled)
  int s0 = rowstart[i], n = degi[i];
  int k = 0;
  for (; k + 3 < n; k += 4) {
    int sA = csr_src[s0 + k];
    int sB = csr_src[s0 + k + 1];
    int sC = csr_src[s0 + k + 2];
    int sD = csr_src[s0 + k + 3];
    float a = bf2f(h2[(size_t)sA * CO + c]);
    float b = bf2f(h2[(size_t)sB * CO + c]);
    float cc = bf2f(h2[(size_t)sC * CO + c]);
    float d = bf2f(h2[(size_t)sD * CO + c]);
    acc += (a + b) + (cc + d);
  }
  for (; k < n; ++k) acc += bf2f(h2[(size_t)csr_src[s0 + k] * CO + c]);
  vals[half][c] = acc * dinv[i] + b2[c];
  if (c == 0) gid[half] = batch[i];
  __syncthreads();
  if (threadIdx.x < 32) {
    int ch = threadIdx.x;
    float run = vals[0][ch];
    int g = gid[0];
    for (int s = 1; s < 8; ++s) {
      if (gid[s] == g) run += vals[s][ch];
      else { atomicAdd(&sums[g * CO + ch], run); g = gid[s]; run = vals[s][ch]; }
    }
    atomicAdd(&sums[g * CO + ch], run);
  }
}

static __global__ void k_final(const float* __restrict__ sums, const float* __restrict__ counts,
                               float* __restrict__ out) {
  int t = blockIdx.x * 256 + threadIdx.x;
  if (t >= NG * CO) return;
  out[t] = sums[t] / fmaxf(counts[t >> 5], 1.0f);
}

extern "C" void kernel_launch(void* const* d_in, const int* in_sizes, int n_in,
                              void* d_out, int out_size, void* d_ws, size_t ws_size,
                              hipStream_t stream) {
  const float* x   = (const float*)d_in[0];
  const int* ei    = (const int*)d_in[1];   // [2, NE]: src = ei, dst = ei+NE
  const int* batch = (const int*)d_in[2];
  const float* W1  = (const float*)d_in[3];
  const float* b1  = (const float*)d_in[4];
  const float* W2  = (const float*)d_in[5];
  const float* b2  = (const float*)d_in[6];
  float* out = (float*)d_out;

  const int* src = ei;
  const int* dst = ei + NE;

  char* base = (char*)d_ws;
  size_t off = 0;
  auto allocB = [&](size_t nbytes) {
    void* p = (void*)(base + off);
    off += ((nbytes + 255) / 256) * 256;
    return p;
  };
  int* degi      = (int*)allocB(NN * 4);
  int* rowstart  = (int*)allocB(NN * 4);
  float* dinv    = (float*)allocB(NN * 4);
  int* bsum      = (int*)allocB(NBLK * 4);
  int* bbase2    = (int*)allocB(NBLK * 4);
  int* bhist     = (int*)allocB(128 * 4);
  int* bbase     = (int*)allocB(129 * 4);
  int* bcursor   = (int*)allocB(128 * 4);
  int* csr_src   = (int*)allocB((size_t)NE * 4);          // 5 MB
  ushortT* hbuf  = (ushortT*)allocB((size_t)NN * CH * 2); // h1 bf16, then h2 bf16
  float* bufB    = (float*)allocB((size_t)NN * CH * 4);   // pairs (5 MB) then agg1 fp32
  float* sums    = (float*)allocB(NG * CO * 4);
  float* counts  = (float*)allocB(NG * 4);
  unsigned int* pairs = (unsigned int*)bufB;  // dead once k_bucket_b finishes

  dim3 B(256);
  // CSR build (bucketed, cache-friendly, packed pairs)
  k_zero<<<dim3(16), B, 0, stream>>>(sums, bhist, batch, counts);
  k_bhist<<<dim3(NBLKP), B, 0, stream>>>(dst, bhist);
  k_bscan<<<dim3(1), dim3(128), 0, stream>>>(bhist, bbase, bcursor);
  k_part<<<dim3(NBLKP), B, 0, stream>>>(src, dst, bcursor, pairs);
  k_bucket_a<<<dim3(NBUCK), B, 0, stream>>>(pairs, bbase, degi, dinv);
  k_scanA<<<dim3(NBLK), B, 0, stream>>>(degi, bsum);
  k_scanB<<<dim3(1), dim3(512), 0, stream>>>(bsum, bbase2);
  k_scanC<<<dim3(NBLK), B, 0, stream>>>(degi, bbase2, rowstart);
  k_bucket_b<<<dim3(NBUCK), B, 0, stream>>>(pairs, bbase, rowstart, csr_src);
  // layer 1
  k_gemm1<<<dim3(GGRID), B, 0, stream>>>(x, W1, dinv, hbuf);
  k_agg64<<<dim3(NN / 4), B, 0, stream>>>(hbuf, dinv, rowstart, degi, csr_src, b1, bufB);
  // layer 2 (bias+relu fused into agg64's write)
  k_gemm2<<<dim3(GGRID), B, 0, stream>>>(bufB, W2, dinv, hbuf);
  k_agg32pool<<<dim3(NN / 8), B, 0, stream>>>(hbuf, dinv, rowstart, degi, csr_src, batch, b2, sums);
  // finalize
  k_final<<<dim3((NG * CO + 255) / 256), B, 0, stream>>>(sums, counts, out);
}